// Round 16
// baseline (95.494 us; speedup 1.0000x reference)
//
#include <hip/hip_runtime.h>
#include <stdint.h>

#define HW    4096      // 64*64
#define CIN   256
#define COUT  512
#define NSPE  64500
#define NFAM  510
#define NORD  100
#define NOUT  65110     // 64500+510+100
#define NSTR  256       // streamer blocks (prefetch head weights into L3)
#define NATT  2048      // attn blocks

typedef __attribute__((ext_vector_type(8))) short bf16x8;
typedef __attribute__((ext_vector_type(4))) float f32x4;
typedef __attribute__((address_space(3))) uint32_t lds_u32;
typedef __attribute__((address_space(1))) const uint32_t glob_u32;

__device__ __forceinline__ short f32_to_bf16(float f) {
    uint32_t u = __float_as_uint(f);
    u += 0x7fffu + ((u >> 16) & 1u);   // RNE
    return (short)(u >> 16);
}
__device__ __forceinline__ float lo16(uint32_t u) {   // low bf16 of a u32 pair
    return __uint_as_float(u << 16);
}
__device__ __forceinline__ float hi16(uint32_t u) {   // high bf16 of a u32 pair
    return __uint_as_float(u & 0xffff0000u);
}

// Tile layout: [128 rows][32 k] bf16, element (row,k) stored at
//   row*32 + ((k>>3 ^ ((row>>1)&3))<<3) + (k&7)     (slot-XOR swizzle)

// ---- unified convert: z<4 -> x slices (batch z), z==4 -> weights ----
__global__ __launch_bounds__(256) void convert_kernel(
    const float* __restrict__ x,
    const float* __restrict__ wq, const float* __restrict__ wk,
    const float* __restrict__ wv,
    short* __restrict__ Xt, short* __restrict__ Wt)
{
    const int t = threadIdx.x;
    __shared__ float lds[32][128];

    if (blockIdx.z < 4) {
        const int kt = blockIdx.x, nt = blockIdx.y, b = blockIdx.z;
        #pragma unroll
        for (int j = 0; j < 16; ++j) {
            int idx = j * 256 + t;
            int c = idx >> 7, p = idx & 127;
            lds[c][p] = x[((size_t)b * CIN + kt * 32 + c) * HW + nt * 128 + p];
        }
        __syncthreads();

        const int n = t >> 1;
        short* out = Xt + (((size_t)(b * 32 + nt) * 8 + kt) << 12);
        union { short s[16]; int4 v[2]; } pk;
        #pragma unroll
        for (int j = 0; j < 16; ++j) {
            int e  = t * 16 + j;
            int sp = (e >> 3) & 3;
            int i  = e & 7;
            int k  = ((sp ^ ((n >> 1) & 3)) << 3) + i;
            pk.s[j] = f32_to_bf16(lds[k][n]);
        }
        int4* dst = (int4*)(out + t * 16);
        dst[0] = pk.v[0];
        dst[1] = pk.v[1];
    } else {
        if (blockIdx.y >= 12) return;
        const int kt = blockIdx.x, mt = blockIdx.y & 3, mat = blockIdx.y >> 2;
        const float* __restrict__ W = (mat == 0) ? wq : (mat == 1) ? wk : wv;
        const int m = t >> 1;
        short* out = Wt + (((size_t)(mat * 4 + mt) * 8 + kt) << 12);

        union { short s[16]; int4 v[2]; } pk;
        #pragma unroll
        for (int j = 0; j < 16; ++j) {
            int e  = t * 16 + j;
            int sp = (e >> 3) & 3;
            int i  = e & 7;
            int k  = ((sp ^ ((m >> 1) & 3)) << 3) + i;
            pk.s[j] = f32_to_bf16(W[(size_t)(mt * 128 + m) * CIN + kt * 32 + k]);
        }
        int4* dst = (int4*)(out + t * 16);
        dst[0] = pk.v[0];
        dst[1] = pk.v[1];
    }
}

// ---- QKV GEMM (R4 config: BM=BN=128, BK=32, 4 waves 2x2, dbuf) ----
__global__ __launch_bounds__(256) void qkv_mfma_kernel(
    const short* __restrict__ Wt, const short* __restrict__ Xt,
    const float* __restrict__ bq, const float* __restrict__ bk,
    const float* __restrict__ bv, short* __restrict__ qkv)
{
    const int nt = blockIdx.x, mt = blockIdx.y, z = blockIdx.z;
    const int mat = z >> 2, b = z & 3;
    const short* At = Wt + (((size_t)(mat * 4 + mt) * 8) << 12);
    const short* Bt = Xt + (((size_t)(b * 32 + nt) * 8) << 12);

    __shared__ __align__(16) short As[2][4096];
    __shared__ __align__(16) short Bs[2][4096];

    const int tid = threadIdx.x, lane = tid & 63, wid = tid >> 6;
    const int wm = wid >> 1, wn = wid & 1;
    const int l15 = lane & 15, sl = lane >> 4;
    const int sw = ((sl ^ ((l15 >> 1) & 3)) << 3);

    f32x4 acc[4][4] = {};

#define STAGE(KT, BUF) do {                                                   \
    _Pragma("unroll")                                                         \
    for (int j = 0; j < 4; ++j) {                                             \
        int li = wid * 4 + j;                                                 \
        if (li < 8)                                                           \
            __builtin_amdgcn_global_load_lds(                                 \
                (glob_u32*)(At + (KT) * 4096 + li * 512 + lane * 8),          \
                (lds_u32*)(&As[BUF][li * 512]), 16, 0, 0);                    \
        else                                                                  \
            __builtin_amdgcn_global_load_lds(                                 \
                (glob_u32*)(Bt + (KT) * 4096 + (li - 8) * 512 + lane * 8),    \
                (lds_u32*)(&Bs[BUF][(li - 8) * 512]), 16, 0, 0);              \
    }                                                                         \
} while (0)

    STAGE(0, 0);
    __syncthreads();

    int buf = 0;
    #pragma unroll 2
    for (int kt = 0; kt < 8; ++kt) {
        if (kt < 7) STAGE(kt + 1, buf ^ 1);

        bf16x8 a[4], bb[4];
        #pragma unroll
        for (int f = 0; f < 4; ++f) {
            int ra = wm * 64 + f * 16 + l15;
            a[f]  = *(const bf16x8*)(&As[buf][ra * 32 + sw]);
            int rb = wn * 64 + f * 16 + l15;
            bb[f] = *(const bf16x8*)(&Bs[buf][rb * 32 + sw]);
        }
        #pragma unroll
        for (int mf = 0; mf < 4; ++mf)
            #pragma unroll
            for (int nf = 0; nf < 4; ++nf)
                acc[mf][nf] = __builtin_amdgcn_mfma_f32_16x16x32_bf16(
                    a[mf], bb[nf], acc[mf][nf], 0, 0, 0);
        __syncthreads();
        buf ^= 1;
    }
#undef STAGE

    const float* bias = (mat == 0) ? bq : (mat == 1) ? bk : bv;
    short* out = qkv + (((size_t)(b * 3 + mat) * COUT + mt * 128) * HW) + nt * 128;
    const int col = lane & 15, g = lane >> 4;
    #pragma unroll
    for (int mf = 0; mf < 4; ++mf) {
        #pragma unroll
        for (int nf = 0; nf < 4; ++nf) {
            #pragma unroll
            for (int r = 0; r < 4; ++r) {
                int m = wm * 64 + mf * 16 + g * 4 + r;
                int n = wn * 64 + nf * 16 + col;
                float val = acc[mf][nf][r] + bias[mt * 128 + m];
                out[(size_t)m * HW + n] = f32_to_bf16(val);
            }
        }
    }
}

// ---- fused streamer + attention kernel ----
// blocks 0..NSTR-1: pure streamers — strided coalesced read of all head
//   weights (133MB) onto attn's idle HBM bandwidth -> L3-resident for heads.
//   No spin, no atomics (R14's acquire-poll thrash avoided), separate blocks
//   (R13's in-block serialization avoided). Exit when done.
// blocks NSTR..NSTR+NATT-1: R11 attn block (c,b); block-uniform isH branch
//   hoisted out of pixel loop; q2 folded into 3-entry qr[] per pixel.
__global__ __launch_bounds__(256, 4) void attn_pool_kernel(
    const unsigned short* __restrict__ qkv,
    const float* __restrict__ rel_h, const float* __restrict__ rel_w,
    const float* __restrict__ w_sp, const float* __restrict__ w_fa,
    const float* __restrict__ w_or,
    float* __restrict__ pooled)   // [4][COUT]
{
    const int bid = blockIdx.x;
    const int tid = threadIdx.x;

    if (bid < NSTR) {
        // =================== streamer block ===================
        const int g = bid * 256 + tid;           // 0..65535
        float s = 0.f;
        const float4* sp4 = reinterpret_cast<const float4*>(w_sp);
        for (int idx = g; idx < 8256000; idx += 65536) {   // 64500*512/4
            float4 t4 = sp4[idx];
            s += t4.x + t4.y + t4.z + t4.w;
        }
        if (g < 65280) {                                   // 510*512/4
            float4 t4 = reinterpret_cast<const float4*>(w_fa)[g];
            s += t4.x + t4.y + t4.z + t4.w;
        }
        if (g < 12800) {                                   // 100*512/4
            float4 t4 = reinterpret_cast<const float4*>(w_or)[g];
            s += t4.x + t4.y + t4.z + t4.w;
        }
        asm volatile("" :: "v"(s));              // keep stream alive (no DCE)
        return;
    }

    // =================== attn block (R11 body) ===================
    const int idx = bid - NSTR;
    const int c = idx & 511;
    const int b = idx >> 9;
    const int h  = tid >> 2;            // 0..63
    const int w0 = (tid & 3) * 16;      // 0,16,32,48

    const unsigned short* qc = qkv + ((size_t)(b * 3 + 0) * COUT + c) * HW;
    const unsigned short* kg = qkv + ((size_t)(b * 3 + 1) * COUT + c) * HW;
    const unsigned short* vg = qkv + ((size_t)(b * 3 + 2) * COUT + c) * HW;

    __shared__ float kS[66 * 67];
    __shared__ float vS[66 * 67];
    __shared__ float red[4];

    // zero pad border
    if (tid < 67) {
        kS[tid] = 0.f;            vS[tid] = 0.f;             // row -1
        kS[65 * 67 + tid] = 0.f;  vS[65 * 67 + tid] = 0.f;   // row 64
    }
    if (tid < 64) {
        int r0 = (tid + 1) * 67;
        kS[r0] = 0.f;       vS[r0] = 0.f;                    // col -1
        kS[r0 + 65] = 0.f;  vS[r0 + 65] = 0.f;               // col 64
    }

    // stage k,v: 2 x uint4 (16 bf16) per thread per array; 1 bit-op per elem
    const uint4* kg4 = reinterpret_cast<const uint4*>(kg);
    const uint4* vg4 = reinterpret_cast<const uint4*>(vg);
    #pragma unroll
    for (int it = 0; it < 2; ++it) {
        int ch = tid + it * 256;
        int y = ch >> 3, xs = (ch & 7) * 8;
        uint4 a = kg4[ch];
        float* kp = &kS[(y + 1) * 67 + xs + 1];
        kp[0] = lo16(a.x); kp[1] = hi16(a.x);
        kp[2] = lo16(a.y); kp[3] = hi16(a.y);
        kp[4] = lo16(a.z); kp[5] = hi16(a.z);
        kp[6] = lo16(a.w); kp[7] = hi16(a.w);
        uint4 d = vg4[ch];
        float* vp = &vS[(y + 1) * 67 + xs + 1];
        vp[0] = lo16(d.x); vp[1] = hi16(d.x);
        vp[2] = lo16(d.y); vp[3] = hi16(d.y);
        vp[4] = lo16(d.z); vp[5] = hi16(d.z);
        vp[6] = lo16(d.w); vp[7] = hi16(d.w);
    }

    // q in regs (log2e folded for exp2-direct softmax)
    const float L2E = 1.4426950408889634f;
    float qf[16];
    {
        uint4 qa = *reinterpret_cast<const uint4*>(qc + h * 64 + w0);
        uint4 qb = *reinterpret_cast<const uint4*>(qc + h * 64 + w0 + 8);
        qf[0]  = lo16(qa.x) * L2E; qf[1]  = hi16(qa.x) * L2E;
        qf[2]  = lo16(qa.y) * L2E; qf[3]  = hi16(qa.y) * L2E;
        qf[4]  = lo16(qa.z) * L2E; qf[5]  = hi16(qa.z) * L2E;
        qf[6]  = lo16(qa.w) * L2E; qf[7]  = hi16(qa.w) * L2E;
        qf[8]  = lo16(qb.x) * L2E; qf[9]  = hi16(qb.x) * L2E;
        qf[10] = lo16(qb.y) * L2E; qf[11] = hi16(qb.y) * L2E;
        qf[12] = lo16(qb.z) * L2E; qf[13] = hi16(qb.z) * L2E;
        qf[14] = lo16(qb.w) * L2E; qf[15] = hi16(qb.w) * L2E;
    }

    // rel values (3 distinct per channel)
    const bool isH = (c < 256);
    float r3[3];
    #pragma unroll
    for (int i = 0; i < 3; ++i)
        r3[i] = isH ? rel_h[c * 3 + i] : rel_w[(c - 256) * 3 + i];

    __syncthreads();

    // window rows h-1..h+1 -> LDS rows h..h+2; px w -> LDS col w+1
    const float* krow = &kS[h * 67 + w0];
    const float* vrow = &vS[h * 67 + w0];

    float kcw[3][3], vcw[3][3];                 // [col-slot][row]
    #pragma unroll
    for (int s = 0; s < 2; ++s)
        #pragma unroll
        for (int r = 0; r < 3; ++r) {
            kcw[s][r] = krow[r * 67 + s];
            vcw[s][r] = vrow[r * 67 + s];
        }

    float total = 0.f;
    // block-uniform branch hoisted: inner elem = 1 fma + 1 exp2 + 1 add + 1 fma
    if (isH) {
        #pragma unroll
        for (int i = 0; i < 16; ++i) {
            const int s2 = (i + 2) % 3;
            #pragma unroll
            for (int r = 0; r < 3; ++r) {
                kcw[s2][r] = krow[r * 67 + i + 2];
                vcw[s2][r] = vrow[r * 67 + i + 2];
            }
            const float q2 = qf[i];
            const float qr[3] = {q2 * r3[0], q2 * r3[1], q2 * r3[2]};
            float num = 0.f, den = 0.f;
            #pragma unroll
            for (int r = 0; r < 3; ++r)
                #pragma unroll
                for (int dx = 0; dx < 3; ++dx) {
                    const int sl = (i + dx) % 3;
                    float e = __builtin_exp2f(fmaf(q2, kcw[sl][r], qr[r]));
                    den += e;
                    num = fmaf(e, vcw[sl][r], num);
                }
            total += fmaxf(num * __builtin_amdgcn_rcpf(den), 0.f);
        }
    } else {
        #pragma unroll
        for (int i = 0; i < 16; ++i) {
            const int s2 = (i + 2) % 3;
            #pragma unroll
            for (int r = 0; r < 3; ++r) {
                kcw[s2][r] = krow[r * 67 + i + 2];
                vcw[s2][r] = vrow[r * 67 + i + 2];
            }
            const float q2 = qf[i];
            const float qr[3] = {q2 * r3[0], q2 * r3[1], q2 * r3[2]};
            float num = 0.f, den = 0.f;
            #pragma unroll
            for (int r = 0; r < 3; ++r)
                #pragma unroll
                for (int dx = 0; dx < 3; ++dx) {
                    const int sl = (i + dx) % 3;
                    float e = __builtin_exp2f(fmaf(q2, kcw[sl][r], qr[dx]));
                    den += e;
                    num = fmaf(e, vcw[sl][r], num);
                }
            total += fmaxf(num * __builtin_amdgcn_rcpf(den), 0.f);
        }
    }

    #pragma unroll
    for (int off = 32; off; off >>= 1) total += __shfl_down(total, off);
    if ((tid & 63) == 0) red[tid >> 6] = total;
    __syncthreads();
    if (tid == 0)
        pooled[b * COUT + c] = (red[0] + red[1] + red[2] + red[3]) * (1.f / 4096.f);
}

// ---- classifier heads ----
__global__ __launch_bounds__(256) void heads_kernel(
    const float* __restrict__ pooled,    // [4][COUT]
    const float* __restrict__ w_sp, const float* __restrict__ b_sp,
    const float* __restrict__ w_fa, const float* __restrict__ b_fa,
    const float* __restrict__ w_or, const float* __restrict__ b_or,
    float* __restrict__ out)             // [4][NOUT]
{
    const int lane   = threadIdx.x & 63;
    const int wave   = blockIdx.x * (blockDim.x >> 6) + (threadIdx.x >> 6);
    const int nwaves = gridDim.x * (blockDim.x >> 6);

    float pr[4][8];
    #pragma unroll
    for (int b = 0; b < 4; ++b)
        #pragma unroll
        for (int e = 0; e < 8; ++e)
            pr[b][e] = pooled[b * COUT + lane * 8 + e];

    for (int j = wave; j < NOUT; j += nwaves) {
        const float* __restrict__ wrow;
        float bias;
        if (j < NSPE)            { wrow = w_sp + (size_t)j * COUT;          bias = b_sp[j]; }
        else if (j < NSPE + NFAM){ wrow = w_fa + (size_t)(j - NSPE) * COUT; bias = b_fa[j - NSPE]; }
        else                     { wrow = w_or + (size_t)(j - NSPE - NFAM) * COUT; bias = b_or[j - NSPE - NFAM]; }

        const float4 w0 = reinterpret_cast<const float4*>(wrow)[lane * 2 + 0];
        const float4 w1 = reinterpret_cast<const float4*>(wrow)[lane * 2 + 1];
        const float we[8] = {w0.x, w0.y, w0.z, w0.w, w1.x, w1.y, w1.z, w1.w};

        float a0 = 0.f, a1 = 0.f, a2 = 0.f, a3 = 0.f;
        #pragma unroll
        for (int e = 0; e < 8; ++e) {
            a0 += we[e] * pr[0][e];
            a1 += we[e] * pr[1][e];
            a2 += we[e] * pr[2][e];
            a3 += we[e] * pr[3][e];
        }
        #pragma unroll
        for (int off = 32; off; off >>= 1) {
            a0 += __shfl_down(a0, off);
            a1 += __shfl_down(a1, off);
            a2 += __shfl_down(a2, off);
            a3 += __shfl_down(a3, off);
        }
        if (lane == 0) {
            out[0 * NOUT + j] = a0 + bias;
            out[1 * NOUT + j] = a1 + bias;
            out[2 * NOUT + j] = a2 + bias;
            out[3 * NOUT + j] = a3 + bias;
        }
    }
}

extern "C" void kernel_launch(void* const* d_in, const int* in_sizes, int n_in,
                              void* d_out, int out_size, void* d_ws, size_t ws_size,
                              hipStream_t stream) {
    const float* x     = (const float*)d_in[0];
    const float* wq    = (const float*)d_in[1];
    const float* bq    = (const float*)d_in[2];
    const float* wk    = (const float*)d_in[3];
    const float* bk    = (const float*)d_in[4];
    const float* wv    = (const float*)d_in[5];
    const float* bv    = (const float*)d_in[6];
    const float* rel_h = (const float*)d_in[7];
    const float* rel_w = (const float*)d_in[8];
    const float* w_sp  = (const float*)d_in[9];
    const float* b_sp  = (const float*)d_in[10];
    const float* w_fa  = (const float*)d_in[11];
    const float* b_fa  = (const float*)d_in[12];
    const float* w_or  = (const float*)d_in[13];
    const float* b_or  = (const float*)d_in[14];
    float* out = (float*)d_out;

    // ws: Wt bf16 | Xt bf16 | qkv bf16 | pooled f32
    short* Wt  = (short*)d_ws;                       // 3*512*256   = 393216
    short* Xt  = Wt + 393216;                        // 4*256*4096  = 4194304
    short* qkv = Xt + 4194304;                       // 4*3*512*4096= 25165824
    float* pooled = (float*)(qkv + 25165824);        // 4*512

    convert_kernel<<<dim3(8, 32, 5), 256, 0, stream>>>(x, wq, wk, wv, Xt, Wt);
    qkv_mfma_kernel<<<dim3(32, 4, 12), 256, 0, stream>>>(Wt, Xt, bq, bk, bv, qkv);
    attn_pool_kernel<<<dim3(NSTR + NATT), 256, 0, stream>>>(
        (const unsigned short*)qkv, rel_h, rel_w, w_sp, w_fa, w_or, pooled);
    heads_kernel<<<dim3(2048), 256, 0, stream>>>(
        pooled, w_sp, b_sp, w_fa, b_fa, w_or, b_or, out);
}

// Round 17
// 80.161 us; speedup vs baseline: 1.1913x; 1.1913x over previous
//
#include <hip/hip_runtime.h>
#include <stdint.h>

#define HW    4096      // 64*64
#define CIN   256
#define COUT  512
#define NSPE  64500
#define NFAM  510
#define NORD  100
#define NOUT  65110     // 64500+510+100

typedef __attribute__((ext_vector_type(8))) short bf16x8;
typedef __attribute__((ext_vector_type(4))) float f32x4;
typedef __attribute__((address_space(3))) uint32_t lds_u32;
typedef __attribute__((address_space(1))) const uint32_t glob_u32;

__device__ __forceinline__ short f32_to_bf16(float f) {
    uint32_t u = __float_as_uint(f);
    u += 0x7fffu + ((u >> 16) & 1u);   // RNE
    return (short)(u >> 16);
}
__device__ __forceinline__ float lo16(uint32_t u) {   // low bf16 of a u32 pair
    return __uint_as_float(u << 16);
}
__device__ __forceinline__ float hi16(uint32_t u) {   // high bf16 of a u32 pair
    return __uint_as_float(u & 0xffff0000u);
}

// Tile layout: [128 rows][32 k] bf16, element (row,k) stored at
//   row*32 + ((k>>3 ^ ((row>>1)&3))<<3) + (k&7)     (slot-XOR swizzle)

// ---- unified convert: z<4 -> x slices (batch z), z==4 -> weights ----
__global__ __launch_bounds__(256) void convert_kernel(
    const float* __restrict__ x,
    const float* __restrict__ wq, const float* __restrict__ wk,
    const float* __restrict__ wv,
    short* __restrict__ Xt, short* __restrict__ Wt)
{
    const int t = threadIdx.x;
    __shared__ float lds[32][128];

    if (blockIdx.z < 4) {
        const int kt = blockIdx.x, nt = blockIdx.y, b = blockIdx.z;
        #pragma unroll
        for (int j = 0; j < 16; ++j) {
            int idx = j * 256 + t;
            int c = idx >> 7, p = idx & 127;
            lds[c][p] = x[((size_t)b * CIN + kt * 32 + c) * HW + nt * 128 + p];
        }
        __syncthreads();

        const int n = t >> 1;
        short* out = Xt + (((size_t)(b * 32 + nt) * 8 + kt) << 12);
        union { short s[16]; int4 v[2]; } pk;
        #pragma unroll
        for (int j = 0; j < 16; ++j) {
            int e  = t * 16 + j;
            int sp = (e >> 3) & 3;
            int i  = e & 7;
            int k  = ((sp ^ ((n >> 1) & 3)) << 3) + i;
            pk.s[j] = f32_to_bf16(lds[k][n]);
        }
        int4* dst = (int4*)(out + t * 16);
        dst[0] = pk.v[0];
        dst[1] = pk.v[1];
    } else {
        if (blockIdx.y >= 12) return;
        const int kt = blockIdx.x, mt = blockIdx.y & 3, mat = blockIdx.y >> 2;
        const float* __restrict__ W = (mat == 0) ? wq : (mat == 1) ? wk : wv;
        const int m = t >> 1;
        short* out = Wt + (((size_t)(mat * 4 + mt) * 8 + kt) << 12);

        union { short s[16]; int4 v[2]; } pk;
        #pragma unroll
        for (int j = 0; j < 16; ++j) {
            int e  = t * 16 + j;
            int sp = (e >> 3) & 3;
            int i  = e & 7;
            int k  = ((sp ^ ((m >> 1) & 3)) << 3) + i;
            pk.s[j] = f32_to_bf16(W[(size_t)(mt * 128 + m) * CIN + kt * 32 + k]);
        }
        int4* dst = (int4*)(out + t * 16);
        dst[0] = pk.v[0];
        dst[1] = pk.v[1];
    }
}

// ---- QKV GEMM (R4 config: BM=BN=128, BK=32, 4 waves 2x2, dbuf) ----
__global__ __launch_bounds__(256) void qkv_mfma_kernel(
    const short* __restrict__ Wt, const short* __restrict__ Xt,
    const float* __restrict__ bq, const float* __restrict__ bk,
    const float* __restrict__ bv, short* __restrict__ qkv)
{
    const int nt = blockIdx.x, mt = blockIdx.y, z = blockIdx.z;
    const int mat = z >> 2, b = z & 3;
    const short* At = Wt + (((size_t)(mat * 4 + mt) * 8) << 12);
    const short* Bt = Xt + (((size_t)(b * 32 + nt) * 8) << 12);

    __shared__ __align__(16) short As[2][4096];
    __shared__ __align__(16) short Bs[2][4096];

    const int tid = threadIdx.x, lane = tid & 63, wid = tid >> 6;
    const int wm = wid >> 1, wn = wid & 1;
    const int l15 = lane & 15, sl = lane >> 4;
    const int sw = ((sl ^ ((l15 >> 1) & 3)) << 3);

    f32x4 acc[4][4] = {};

#define STAGE(KT, BUF) do {                                                   \
    _Pragma("unroll")                                                         \
    for (int j = 0; j < 4; ++j) {                                             \
        int li = wid * 4 + j;                                                 \
        if (li < 8)                                                           \
            __builtin_amdgcn_global_load_lds(                                 \
                (glob_u32*)(At + (KT) * 4096 + li * 512 + lane * 8),          \
                (lds_u32*)(&As[BUF][li * 512]), 16, 0, 0);                    \
        else                                                                  \
            __builtin_amdgcn_global_load_lds(                                 \
                (glob_u32*)(Bt + (KT) * 4096 + (li - 8) * 512 + lane * 8),    \
                (lds_u32*)(&Bs[BUF][(li - 8) * 512]), 16, 0, 0);              \
    }                                                                         \
} while (0)

    STAGE(0, 0);
    __syncthreads();

    int buf = 0;
    #pragma unroll 2
    for (int kt = 0; kt < 8; ++kt) {
        if (kt < 7) STAGE(kt + 1, buf ^ 1);

        bf16x8 a[4], bb[4];
        #pragma unroll
        for (int f = 0; f < 4; ++f) {
            int ra = wm * 64 + f * 16 + l15;
            a[f]  = *(const bf16x8*)(&As[buf][ra * 32 + sw]);
            int rb = wn * 64 + f * 16 + l15;
            bb[f] = *(const bf16x8*)(&Bs[buf][rb * 32 + sw]);
        }
        #pragma unroll
        for (int mf = 0; mf < 4; ++mf)
            #pragma unroll
            for (int nf = 0; nf < 4; ++nf)
                acc[mf][nf] = __builtin_amdgcn_mfma_f32_16x16x32_bf16(
                    a[mf], bb[nf], acc[mf][nf], 0, 0, 0);
        __syncthreads();
        buf ^= 1;
    }
#undef STAGE

    const float* bias = (mat == 0) ? bq : (mat == 1) ? bk : bv;
    short* out = qkv + (((size_t)(b * 3 + mat) * COUT + mt * 128) * HW) + nt * 128;
    const int col = lane & 15, g = lane >> 4;
    #pragma unroll
    for (int mf = 0; mf < 4; ++mf) {
        #pragma unroll
        for (int nf = 0; nf < 4; ++nf) {
            #pragma unroll
            for (int r = 0; r < 4; ++r) {
                int m = wm * 64 + mf * 16 + g * 4 + r;
                int n = wn * 64 + nf * 16 + col;
                float val = acc[mf][nf][r] + bias[mt * 128 + m];
                out[(size_t)m * HW + n] = f32_to_bf16(val);
            }
        }
    }
}

// ---- attention + relu + pool: R11 structure + isolated VALU cut ----
// One block per (c,b); single-buffer f32 LDS (35.4 KB, 4 blocks/CU);
// block-uniform isH branch hoisted out of the pixel loop; rel folded as
// qr[] = q2*r3[] so inner element = fma + exp2 + add + fma.
__global__ __launch_bounds__(256, 4) void attn_pool_kernel(
    const unsigned short* __restrict__ qkv,
    const float* __restrict__ rel_h, const float* __restrict__ rel_w,
    float* __restrict__ pooled)   // [4][COUT]
{
    const int c = blockIdx.x;
    const int b = blockIdx.y;
    const int tid = threadIdx.x;
    const int h  = tid >> 2;            // 0..63
    const int w0 = (tid & 3) * 16;      // 0,16,32,48

    const unsigned short* qc = qkv + ((size_t)(b * 3 + 0) * COUT + c) * HW;
    const unsigned short* kg = qkv + ((size_t)(b * 3 + 1) * COUT + c) * HW;
    const unsigned short* vg = qkv + ((size_t)(b * 3 + 2) * COUT + c) * HW;

    __shared__ float kS[66 * 67];
    __shared__ float vS[66 * 67];
    __shared__ float red[4];

    // zero pad border
    if (tid < 67) {
        kS[tid] = 0.f;            vS[tid] = 0.f;             // row -1
        kS[65 * 67 + tid] = 0.f;  vS[65 * 67 + tid] = 0.f;   // row 64
    }
    if (tid < 64) {
        int r0 = (tid + 1) * 67;
        kS[r0] = 0.f;       vS[r0] = 0.f;                    // col -1
        kS[r0 + 65] = 0.f;  vS[r0 + 65] = 0.f;               // col 64
    }

    // stage k,v: 2 x uint4 (16 bf16) per thread per array; 1 bit-op per elem
    const uint4* kg4 = reinterpret_cast<const uint4*>(kg);
    const uint4* vg4 = reinterpret_cast<const uint4*>(vg);
    #pragma unroll
    for (int it = 0; it < 2; ++it) {
        int ch = tid + it * 256;
        int y = ch >> 3, xs = (ch & 7) * 8;
        uint4 a = kg4[ch];
        float* kp = &kS[(y + 1) * 67 + xs + 1];
        kp[0] = lo16(a.x); kp[1] = hi16(a.x);
        kp[2] = lo16(a.y); kp[3] = hi16(a.y);
        kp[4] = lo16(a.z); kp[5] = hi16(a.z);
        kp[6] = lo16(a.w); kp[7] = hi16(a.w);
        uint4 d = vg4[ch];
        float* vp = &vS[(y + 1) * 67 + xs + 1];
        vp[0] = lo16(d.x); vp[1] = hi16(d.x);
        vp[2] = lo16(d.y); vp[3] = hi16(d.y);
        vp[4] = lo16(d.z); vp[5] = hi16(d.z);
        vp[6] = lo16(d.w); vp[7] = hi16(d.w);
    }

    // q in regs (log2e folded for exp2-direct softmax)
    const float L2E = 1.4426950408889634f;
    float qf[16];
    {
        uint4 qa = *reinterpret_cast<const uint4*>(qc + h * 64 + w0);
        uint4 qb = *reinterpret_cast<const uint4*>(qc + h * 64 + w0 + 8);
        qf[0]  = lo16(qa.x) * L2E; qf[1]  = hi16(qa.x) * L2E;
        qf[2]  = lo16(qa.y) * L2E; qf[3]  = hi16(qa.y) * L2E;
        qf[4]  = lo16(qa.z) * L2E; qf[5]  = hi16(qa.z) * L2E;
        qf[6]  = lo16(qa.w) * L2E; qf[7]  = hi16(qa.w) * L2E;
        qf[8]  = lo16(qb.x) * L2E; qf[9]  = hi16(qb.x) * L2E;
        qf[10] = lo16(qb.y) * L2E; qf[11] = hi16(qb.y) * L2E;
        qf[12] = lo16(qb.z) * L2E; qf[13] = hi16(qb.z) * L2E;
        qf[14] = lo16(qb.w) * L2E; qf[15] = hi16(qb.w) * L2E;
    }

    // rel values (3 distinct per channel)
    const bool isH = (c < 256);
    float r3[3];
    #pragma unroll
    for (int i = 0; i < 3; ++i)
        r3[i] = isH ? rel_h[c * 3 + i] : rel_w[(c - 256) * 3 + i];

    __syncthreads();

    // window rows h-1..h+1 -> LDS rows h..h+2; px w -> LDS col w+1
    const float* krow = &kS[h * 67 + w0];
    const float* vrow = &vS[h * 67 + w0];

    float kcw[3][3], vcw[3][3];                 // [col-slot][row]
    #pragma unroll
    for (int s = 0; s < 2; ++s)
        #pragma unroll
        for (int r = 0; r < 3; ++r) {
            kcw[s][r] = krow[r * 67 + s];
            vcw[s][r] = vrow[r * 67 + s];
        }

    float total = 0.f;
    if (isH) {        // rel indexed by window ROW
        #pragma unroll
        for (int i = 0; i < 16; ++i) {
            const int s2 = (i + 2) % 3;
            #pragma unroll
            for (int r = 0; r < 3; ++r) {
                kcw[s2][r] = krow[r * 67 + i + 2];
                vcw[s2][r] = vrow[r * 67 + i + 2];
            }
            const float q2 = qf[i];
            const float qr[3] = {q2 * r3[0], q2 * r3[1], q2 * r3[2]};
            float num = 0.f, den = 0.f;
            #pragma unroll
            for (int r = 0; r < 3; ++r)
                #pragma unroll
                for (int dx = 0; dx < 3; ++dx) {
                    const int sl = (i + dx) % 3;
                    float e = __builtin_exp2f(fmaf(q2, kcw[sl][r], qr[r]));
                    den += e;
                    num = fmaf(e, vcw[sl][r], num);
                }
            total += fmaxf(num * __builtin_amdgcn_rcpf(den), 0.f);
        }
    } else {          // rel indexed by window COLUMN
        #pragma unroll
        for (int i = 0; i < 16; ++i) {
            const int s2 = (i + 2) % 3;
            #pragma unroll
            for (int r = 0; r < 3; ++r) {
                kcw[s2][r] = krow[r * 67 + i + 2];
                vcw[s2][r] = vrow[r * 67 + i + 2];
            }
            const float q2 = qf[i];
            const float qr[3] = {q2 * r3[0], q2 * r3[1], q2 * r3[2]};
            float num = 0.f, den = 0.f;
            #pragma unroll
            for (int r = 0; r < 3; ++r)
                #pragma unroll
                for (int dx = 0; dx < 3; ++dx) {
                    const int sl = (i + dx) % 3;
                    float e = __builtin_exp2f(fmaf(q2, kcw[sl][r], qr[dx]));
                    den += e;
                    num = fmaf(e, vcw[sl][r], num);
                }
            total += fmaxf(num * __builtin_amdgcn_rcpf(den), 0.f);
        }
    }

    #pragma unroll
    for (int off = 32; off; off >>= 1) total += __shfl_down(total, off);
    if ((tid & 63) == 0) red[tid >> 6] = total;
    __syncthreads();
    if (tid == 0)
        pooled[b * COUT + c] = (red[0] + red[1] + red[2] + red[3]) * (1.f / 4096.f);
}

// ---- classifier heads ----
__global__ __launch_bounds__(256) void heads_kernel(
    const float* __restrict__ pooled,    // [4][COUT]
    const float* __restrict__ w_sp, const float* __restrict__ b_sp,
    const float* __restrict__ w_fa, const float* __restrict__ b_fa,
    const float* __restrict__ w_or, const float* __restrict__ b_or,
    float* __restrict__ out)             // [4][NOUT]
{
    const int lane   = threadIdx.x & 63;
    const int wave   = blockIdx.x * (blockDim.x >> 6) + (threadIdx.x >> 6);
    const int nwaves = gridDim.x * (blockDim.x >> 6);

    float pr[4][8];
    #pragma unroll
    for (int b = 0; b < 4; ++b)
        #pragma unroll
        for (int e = 0; e < 8; ++e)
            pr[b][e] = pooled[b * COUT + lane * 8 + e];

    for (int j = wave; j < NOUT; j += nwaves) {
        const float* __restrict__ wrow;
        float bias;
        if (j < NSPE)            { wrow = w_sp + (size_t)j * COUT;          bias = b_sp[j]; }
        else if (j < NSPE + NFAM){ wrow = w_fa + (size_t)(j - NSPE) * COUT; bias = b_fa[j - NSPE]; }
        else                     { wrow = w_or + (size_t)(j - NSPE - NFAM) * COUT; bias = b_or[j - NSPE - NFAM]; }

        const float4 w0 = reinterpret_cast<const float4*>(wrow)[lane * 2 + 0];
        const float4 w1 = reinterpret_cast<const float4*>(wrow)[lane * 2 + 1];
        const float we[8] = {w0.x, w0.y, w0.z, w0.w, w1.x, w1.y, w1.z, w1.w};

        float a0 = 0.f, a1 = 0.f, a2 = 0.f, a3 = 0.f;
        #pragma unroll
        for (int e = 0; e < 8; ++e) {
            a0 += we[e] * pr[0][e];
            a1 += we[e] * pr[1][e];
            a2 += we[e] * pr[2][e];
            a3 += we[e] * pr[3][e];
        }
        #pragma unroll
        for (int off = 32; off; off >>= 1) {
            a0 += __shfl_down(a0, off);
            a1 += __shfl_down(a1, off);
            a2 += __shfl_down(a2, off);
            a3 += __shfl_down(a3, off);
        }
        if (lane == 0) {
            out[0 * NOUT + j] = a0 + bias;
            out[1 * NOUT + j] = a1 + bias;
            out[2 * NOUT + j] = a2 + bias;
            out[3 * NOUT + j] = a3 + bias;
        }
    }
}

extern "C" void kernel_launch(void* const* d_in, const int* in_sizes, int n_in,
                              void* d_out, int out_size, void* d_ws, size_t ws_size,
                              hipStream_t stream) {
    const float* x     = (const float*)d_in[0];
    const float* wq    = (const float*)d_in[1];
    const float* bq    = (const float*)d_in[2];
    const float* wk    = (const float*)d_in[3];
    const float* bk    = (const float*)d_in[4];
    const float* wv    = (const float*)d_in[5];
    const float* bv    = (const float*)d_in[6];
    const float* rel_h = (const float*)d_in[7];
    const float* rel_w = (const float*)d_in[8];
    const float* w_sp  = (const float*)d_in[9];
    const float* b_sp  = (const float*)d_in[10];
    const float* w_fa  = (const float*)d_in[11];
    const float* b_fa  = (const float*)d_in[12];
    const float* w_or  = (const float*)d_in[13];
    const float* b_or  = (const float*)d_in[14];
    float* out = (float*)d_out;

    // ws: Wt bf16 | Xt bf16 | qkv bf16 | pooled f32
    short* Wt  = (short*)d_ws;                       // 3*512*256   = 393216
    short* Xt  = Wt + 393216;                        // 4*256*4096  = 4194304
    short* qkv = Xt + 4194304;                       // 4*3*512*4096= 25165824
    float* pooled = (float*)(qkv + 25165824);        // 4*512

    convert_kernel<<<dim3(8, 32, 5), 256, 0, stream>>>(x, wq, wk, wv, Xt, Wt);
    qkv_mfma_kernel<<<dim3(32, 4, 12), 256, 0, stream>>>(Wt, Xt, bq, bk, bv, qkv);
    attn_pool_kernel<<<dim3(COUT, 4), 256, 0, stream>>>(
        (const unsigned short*)qkv, rel_h, rel_w, pooled);
    heads_kernel<<<dim3(2048), 256, 0, stream>>>(
        pooled, w_sp, b_sp, w_fa, b_fa, w_or, b_or, out);
}